// Round 3
// baseline (250.617 us; speedup 1.0000x reference)
//
#include <hip/hip_runtime.h>

#define BN 32768
#define IN 512
#define NE 8
#define NH 128
#define MO 256

typedef const __attribute__((address_space(1))) unsigned int gu32;
typedef __attribute__((address_space(3))) unsigned int lu32;
typedef __attribute__((ext_vector_type(8))) short bf16x8;
typedef __attribute__((ext_vector_type(4))) float f32x4;

// async global->LDS, 16B per lane. LDS dest = wave-uniform base + lane*16.
__device__ __forceinline__ void cp16(const float* g, float* l) {
    __builtin_amdgcn_global_load_lds((gu32*)g, (lu32*)l, 16, 0, 0);
}

// f32 -> bf16 bits, round-to-nearest-even
__device__ __forceinline__ unsigned short f2bf(float f) {
    unsigned int u = __float_as_uint(f);
    u = (u + 0x7fffu + ((u >> 16) & 1u)) >> 16;
    return (unsigned short)u;
}
__device__ __forceinline__ float bf2f(unsigned short h) {
    return __uint_as_float((unsigned int)h << 16);
}

// ---------------- gating: f32 logits + exact-f64 fallback at near-ties ------
// One thread per (row, expert). Ranking only needs f64 when the rank2/rank3
// margin is below the f32 dot error (~6e-6); threshold 2e-4 is 30x that.
// Expected fallback rows: ~16 of 32768 -> negligible cost.
__global__ __launch_bounds__(256) void gate_kernel(
    const float* __restrict__ x, const float* __restrict__ wg,
    int* __restrict__ gcount, int* __restrict__ gload, float* __restrict__ gimp,
    int* __restrict__ idx_list, float* __restrict__ gate_list,
    float* __restrict__ out, const float* __restrict__ bout)
{
    __shared__ float wgs[NE][516];   // stride 516: 4e+4j banks, conflict-free
    __shared__ int counts_s[NE];
    __shared__ int load_s[NE];
    __shared__ float imp_s[NE];
    __shared__ int base_s[NE];
    __shared__ int rec_e[64];
    __shared__ int rec_p[64];
    __shared__ float rec_g[64];

    int tid = threadIdx.x;
    if (tid < NE) { counts_s[tid] = 0; load_s[tid] = 0; imp_s[tid] = 0.f; }
    if (tid < 64) {  // fused init: out[row, j] = bout[j]
        int row = blockIdx.x * 32 + (tid >> 1);
        out[row * 2 + (tid & 1)] = bout[tid & 1];
    }
    for (int i = tid; i < IN * NE; i += 256) wgs[i & 7][i >> 3] = wg[i];
    __syncthreads();

    int r = tid >> 3;
    int e = tid & 7;
    int row = blockIdx.x * 32 + r;

    const float4* x4 = (const float4*)(x + (size_t)row * IN);
    float a0 = 0.f, a1 = 0.f, a2 = 0.f, a3 = 0.f;
    #pragma unroll 8
    for (int j = 0; j < 128; ++j) {
        float4 xv = x4[j];
        float4 wv = *(const float4*)&wgs[e][4 * j];
        a0 = fmaf(xv.x, wv.x, a0);
        a1 = fmaf(xv.y, wv.y, a1);
        a2 = fmaf(xv.z, wv.z, a2);
        a3 = fmaf(xv.w, wv.w, a3);
    }
    float acc = (a0 + a1) + (a2 + a3);

    // top-1 / top-2 / top-3(value) over the 8-lane group
    float v0 = acc; int e0 = e;
    #pragma unroll
    for (int m = 1; m < 8; m <<= 1) {
        float vo = __shfl_xor(v0, m, 64);
        int eo = __shfl_xor(e0, m, 64);
        if (vo > v0 || (vo == v0 && eo < e0)) { v0 = vo; e0 = eo; }
    }
    float v1 = (e == e0) ? -1e30f : acc; int e1 = e;
    #pragma unroll
    for (int m = 1; m < 8; m <<= 1) {
        float vo = __shfl_xor(v1, m, 64);
        int eo = __shfl_xor(e1, m, 64);
        if (vo > v1 || (vo == v1 && eo < e1)) { v1 = vo; e1 = eo; }
    }
    float v2 = (e == e0 || e == e1) ? -1e30f : acc;
    #pragma unroll
    for (int m = 1; m < 8; m <<= 1) v2 = fmaxf(v2, __shfl_xor(v2, m, 64));

    double dv0 = v0, dv1 = v1;
    int f0 = e0, f1 = e1;
    if (v1 - v2 < 2e-4f) {   // group-uniform: rare exact recompute
        const float* xr = x + (size_t)row * IN;
        double b0 = 0, b1d = 0, b2d = 0, b3 = 0;
        for (int k = 0; k < IN; k += 4) {
            b0  = fma((double)xr[k],     (double)wgs[e][k],     b0);
            b1d = fma((double)xr[k + 1], (double)wgs[e][k + 1], b1d);
            b2d = fma((double)xr[k + 2], (double)wgs[e][k + 2], b2d);
            b3  = fma((double)xr[k + 3], (double)wgs[e][k + 3], b3);
        }
        double ad = (b0 + b1d) + (b2d + b3);
        double w0 = ad; int g0i = e;
        #pragma unroll
        for (int m = 1; m < 8; m <<= 1) {
            double vo = __shfl_xor(w0, m, 64);
            int eo = __shfl_xor(g0i, m, 64);
            if (vo > w0 || (vo == w0 && eo < g0i)) { w0 = vo; g0i = eo; }
        }
        double w1 = (e == g0i) ? -1.0e300 : ad; int g1i = e;
        #pragma unroll
        for (int m = 1; m < 8; m <<= 1) {
            double vo = __shfl_xor(w1, m, 64);
            int eo = __shfl_xor(g1i, m, 64);
            if (vo > w1 || (vo == w1 && eo < g1i)) { w1 = vo; g1i = eo; }
        }
        dv0 = w0; dv1 = w1; f0 = g0i; f1 = g1i;
    }

    if ((tid & 7) == 0) {
        float t1 = expf((float)(dv1 - dv0));
        float s = 1.f + t1;
        float g0 = 1.f / s;
        float g1 = t1 / s;
        atomicAdd(&imp_s[f0], g0);
        atomicAdd(&imp_s[f1], g1);
        if (g0 > 0.f) atomicAdd(&load_s[f0], 1);
        if (g1 > 0.f) atomicAdd(&load_s[f1], 1);
        int p0 = atomicAdd(&counts_s[f0], 1);
        int p1 = atomicAdd(&counts_s[f1], 1);
        int rl = r * 2;
        rec_e[rl] = f0; rec_e[rl + 1] = f1;
        rec_g[rl] = g0; rec_g[rl + 1] = g1;
        rec_p[rl] = p0; rec_p[rl + 1] = p1;
    }
    __syncthreads();
    if (tid < NE) {
        base_s[tid] = atomicAdd(&gcount[tid], counts_s[tid]);
        atomicAdd(&gimp[tid], imp_s[tid]);
        atomicAdd(&gload[tid], load_s[tid]);
    }
    __syncthreads();
    if (tid < 64) {
        int ee = rec_e[tid];
        int pos = base_s[ee] + rec_p[tid];
        int rw = blockIdx.x * 32 + (tid >> 1);
        idx_list[ee * BN + pos] = rw;
        gate_list[ee * BN + pos] = rec_g[tid];
    }
}

// ---------------- weight prep: split bf16 + MFMA-fragment-order blobs -------
__global__ __launch_bounds__(256) void prep_kernel(
    const float* __restrict__ W1, const float* __restrict__ W2,
    float* __restrict__ W1F, float* __restrict__ W2F)
{
    __shared__ __align__(16) char pb[32768];
    int t = threadIdx.x, b = blockIdx.x;
    if (b < 64) {                       // W1: e = b>>3, ktile(64 k) = b&7
        int e = b >> 3, kt = b & 7;
        const float* src = W1 + ((size_t)e * IN + kt * 64) * NH;
        #pragma unroll
        for (int p = 0; p < 8; ++p) {
            int li = p * 256 + t;
            float4 q = *(const float4*)(src + li * 4);
            int kl = li >> 5, n0 = (li & 31) * 4;
            int ks = kl >> 5, g = (kl >> 3) & 3, kb = (kl & 7) * 2;
            float vv[4] = {q.x, q.y, q.z, q.w};
            #pragma unroll
            for (int j = 0; j < 4; ++j) {
                int n = n0 + j;
                int off = (((ks * 8 + (n >> 4)) * 64) + (n & 15) + 16 * g) * 16 + kb;
                unsigned short hh = f2bf(vv[j]);
                unsigned short hl = f2bf(vv[j] - bf2f(hh));
                *(unsigned short*)(pb + off) = hh;
                *(unsigned short*)(pb + 16384 + off) = hl;
            }
        }
        __syncthreads();
        float* dst = W1F + (size_t)b * 8192;
        #pragma unroll
        for (int p = 0; p < 8; ++p) {
            int li = p * 256 + t;
            *(int4*)(dst + li * 4) = *(const int4*)(pb + li * 16);
        }
    } else if (b < 96) {                // W2: e = bi>>2, ktile(32 k) = bi&3
        int bi = b - 64;
        int e = bi >> 2, kt = bi & 3;
        const float* src = W2 + ((size_t)e * NH + kt * 32) * MO;
        #pragma unroll
        for (int p = 0; p < 8; ++p) {
            int li = p * 256 + t;
            float4 q = *(const float4*)(src + li * 4);
            int kl = li >> 6, n0 = (li & 63) * 4;
            int g = kl >> 3, kb = (kl & 7) * 2;
            float vv[4] = {q.x, q.y, q.z, q.w};
            #pragma unroll
            for (int j = 0; j < 4; ++j) {
                int n = n0 + j;
                int off = ((n >> 4) * 64 + (n & 15) + 16 * g) * 16 + kb;
                unsigned short hh = f2bf(vv[j]);
                unsigned short hl = f2bf(vv[j] - bf2f(hh));
                *(unsigned short*)(pb + off) = hh;
                *(unsigned short*)(pb + 16384 + off) = hl;
            }
        }
        __syncthreads();
        float* dst = W2F + (size_t)bi * 8192;
        #pragma unroll
        for (int p = 0; p < 8; ++p) {
            int li = p * 256 + t;
            *(int4*)(dst + li * 4) = *(const int4*)(pb + li * 16);
        }
    }
}

// ---------------- expert compute: pipelined split-bf16 MFMA -----------------
// A-frags loaded directly from global in fragment layout (no A-LDS), W-blobs
// double-buffered with issue-early STAGE (one barrier per K-tile), epilogue
// softmax fully cross-lane (no z-buffer). LDS = 68KB -> 2 blocks/CU.
__global__ __launch_bounds__(256, 2) void expert_kernel(
    const float* __restrict__ x,
    const float* __restrict__ b1, const float* __restrict__ b2,
    const float* __restrict__ Wout,
    const float* __restrict__ W1F, const float* __restrict__ W2F,
    const int* __restrict__ gcount,
    const float* __restrict__ gimp, const int* __restrict__ gload,
    const int* __restrict__ idx_list, const float* __restrict__ gate_list,
    float* __restrict__ out)
{
    __shared__ __align__(16) char buf0[32768];
    __shared__ __align__(16) char buf1[32768];
    __shared__ float woutS[512];
    __shared__ float redm[64][2];
    __shared__ float red3[64][2][3];

    int e = blockIdx.y;
    int cnt = gcount[e];
    int row0 = blockIdx.x * 64;
    // fused load-balancing loss (one thread device-wide)
    if (e == 0 && blockIdx.x == 0 && threadIdx.x == 0) {
        float mi = 0.f, ml = 0.f;
        for (int k = 0; k < NE; ++k) { mi += gimp[k]; ml += (float)gload[k]; }
        mi *= 0.125f; ml *= 0.125f;
        float vi = 0.f, vl = 0.f;
        for (int k = 0; k < NE; ++k) {
            float d = gimp[k] - mi;  vi += d * d;
            float d2 = (float)gload[k] - ml; vl += d2 * d2;
        }
        vi *= (1.f / 7.f); vl *= (1.f / 7.f);
        out[BN * 2] = (vi / (mi * mi + 1e-10f) + vl / (ml * ml + 1e-10f)) * 0.01f;
    }
    if (row0 >= cnt) return;
    int t = threadIdx.x;
    int l = t & 63, w = t >> 6;
    int halfM = w & 1;     // rows halfM*32 .. +31
    int nsel = w >> 1;     // col half

    woutS[t] = Wout[t];
    woutS[256 + t] = Wout[256 + t];

    // A-fragment row pointers (lane = row l&15 within frag, k-offset 8*(l>>4))
    int rA = row0 + halfM * 32 + (l & 15);
    int rB = rA + 16;
    int iA = idx_list[e * BN + (rA < cnt ? rA : cnt - 1)];
    int iB = idx_list[e * BN + (rB < cnt ? rB : cnt - 1)];
    const float* pA = x + (size_t)iA * IN + 8 * (l >> 4);
    const float* pB = x + (size_t)iB * IN + 8 * (l >> 4);

    // prologue: stage W1 blob kt=0 into buf0
    {
        const float* gb = W1F + (size_t)(e * 8) * 8192;
        float* lb = (float*)buf0;
        #pragma unroll
        for (int p = 0; p < 8; ++p)
            cp16(gb + (p * 256 + t) * 4, lb + (p * 256 + t) * 4);
    }
    __syncthreads();

    // ---- stage 1: H[64x128] = relu(X @ W1 + b1), 8 K-tiles of 64 ----
    f32x4 acc1[2][4] = {};
    for (int kt = 0; kt < 8; ++kt) {
        // 1) A loads first (so their wait doesn't drain the prefetch DMA)
        float4 ra[2][2][2];
        #pragma unroll
        for (int mf = 0; mf < 2; ++mf) {
            const float* pp = mf ? pB : pA;
            #pragma unroll
            for (int ks = 0; ks < 2; ++ks) {
                ra[mf][ks][0] = *(const float4*)(pp + kt * 64 + ks * 32);
                ra[mf][ks][1] = *(const float4*)(pp + kt * 64 + ks * 32 + 4);
            }
        }
        // 2) prefetch next blob: kt<7 -> W1[kt+1]; kt==7 -> W2[0]. dest toggles.
        {
            const float* gb = (kt < 7) ? (W1F + (size_t)(e * 8 + kt + 1) * 8192)
                                       : (W2F + (size_t)(e * 4) * 8192);
            float* lb = (float*)((kt & 1) ? buf0 : buf1);
            #pragma unroll
            for (int p = 0; p < 8; ++p)
                cp16(gb + (p * 256 + t) * 4, lb + (p * 256 + t) * 4);
        }
        // 3) split A to hi/lo bf16 fragments in-register
        bf16x8 ah[2][2], al[2][2];
        #pragma unroll
        for (int mf = 0; mf < 2; ++mf)
            #pragma unroll
            for (int ks = 0; ks < 2; ++ks) {
                float v[8] = {ra[mf][ks][0].x, ra[mf][ks][0].y, ra[mf][ks][0].z, ra[mf][ks][0].w,
                              ra[mf][ks][1].x, ra[mf][ks][1].y, ra[mf][ks][1].z, ra[mf][ks][1].w};
                #pragma unroll
                for (int i = 0; i < 8; ++i) {
                    unsigned short h = f2bf(v[i]);
                    ah[mf][ks][i] = (short)h;
                    al[mf][ks][i] = (short)f2bf(v[i] - bf2f(h));
                }
            }
        // 4) MFMA over current buffer
        const char* bb = (kt & 1) ? buf1 : buf0;
        #pragma unroll
        for (int ks = 0; ks < 2; ++ks)
            #pragma unroll
            for (int nf = 0; nf < 4; ++nf) {
                int bo = ((ks * 8 + nsel * 4 + nf) * 64 + l) * 16;
                bf16x8 bh = *(const bf16x8*)(bb + bo);
                bf16x8 bl = *(const bf16x8*)(bb + 16384 + bo);
                #pragma unroll
                for (int mf = 0; mf < 2; ++mf) {
                    acc1[mf][nf] = __builtin_amdgcn_mfma_f32_16x16x32_bf16(ah[mf][ks], bh, acc1[mf][nf], 0, 0, 0);
                    acc1[mf][nf] = __builtin_amdgcn_mfma_f32_16x16x32_bf16(ah[mf][ks], bl, acc1[mf][nf], 0, 0, 0);
                    acc1[mf][nf] = __builtin_amdgcn_mfma_f32_16x16x32_bf16(al[mf][ks], bh, acc1[mf][nf], 0, 0, 0);
                    acc1[mf][nf] = __builtin_amdgcn_mfma_f32_16x16x32_bf16(al[mf][ks], bl, acc1[mf][nf], 0, 0, 0);
                }
            }
        // 5) one barrier per tile (drains prefetch DMA that flew during 3+4)
        __syncthreads();
    }

    // ---- relu(+b1), split, write H as stage-2 A-fragments into buf1 ----
    #pragma unroll
    for (int mf = 0; mf < 2; ++mf) {
        int mf2 = halfM * 2 + mf;
        int rlow = 4 * (l >> 4);
        #pragma unroll
        for (int nf = 0; nf < 4; ++nf) {
            int c = nsel * 64 + nf * 16 + (l & 15);
            float b1v = b1[e * NH + c];
            int ks2 = c >> 5;
            int g2 = (c >> 3) & 3;
            int boff = ((ks2 * 4 + mf2) * 64) * 16 + (c & 7) * 2;
            #pragma unroll
            for (int rg = 0; rg < 4; ++rg) {
                float v = fmaxf(acc1[mf][nf][rg] + b1v, 0.f);
                unsigned short hh = f2bf(v);
                unsigned short hl = f2bf(v - bf2f(hh));
                int off = boff + ((rlow + rg) + 16 * g2) * 16;
                *(unsigned short*)(buf1 + off) = hh;
                *(unsigned short*)(buf1 + 16384 + off) = hl;
            }
        }
    }

    // ---- stage 2: Z[64x256] = H @ W2, 4 K-tiles of 32; B2 in buf0 ----
    f32x4 acc2[2][8] = {};
    for (int kt2 = 0; kt2 < 4; ++kt2) {
        __syncthreads();   // kt2=0: covers HH/HL writes + prefetched B2(0)
        bf16x8 ah2[2], al2[2];
        #pragma unroll
        for (int mf = 0; mf < 2; ++mf) {
            int ao = ((kt2 * 4 + halfM * 2 + mf) * 64 + l) * 16;
            ah2[mf] = *(const bf16x8*)(buf1 + ao);
            al2[mf] = *(const bf16x8*)(buf1 + 16384 + ao);
        }
        #pragma unroll
        for (int nf = 0; nf < 8; ++nf) {
            int bo = ((nsel * 8 + nf) * 64 + l) * 16;
            bf16x8 bh = *(const bf16x8*)(buf0 + bo);
            bf16x8 bl = *(const bf16x8*)(buf0 + 16384 + bo);
            #pragma unroll
            for (int mf = 0; mf < 2; ++mf) {
                acc2[mf][nf] = __builtin_amdgcn_mfma_f32_16x16x32_bf16(ah2[mf], bh, acc2[mf][nf], 0, 0, 0);
                acc2[mf][nf] = __builtin_amdgcn_mfma_f32_16x16x32_bf16(ah2[mf], bl, acc2[mf][nf], 0, 0, 0);
                acc2[mf][nf] = __builtin_amdgcn_mfma_f32_16x16x32_bf16(al2[mf], bh, acc2[mf][nf], 0, 0, 0);
                acc2[mf][nf] = __builtin_amdgcn_mfma_f32_16x16x32_bf16(al2[mf], bl, acc2[mf][nf], 0, 0, 0);
            }
        }
        if (kt2 < 3) {
            __syncthreads();   // all waves done reading buf0 tile
            const float* gb = W2F + (size_t)(e * 4 + kt2 + 1) * 8192;
            float* lb = (float*)buf0;
            #pragma unroll
            for (int p = 0; p < 8; ++p)
                cp16(gb + (p * 256 + t) * 4, lb + (p * 256 + t) * 4);
        }
    }

    // ---- epilogue: in-register softmax over 256 cols, fused @Wout ----
    // lane holds cols c = nsel*128 + nf*16 + (l&15), rows 4*(l>>4)+rg per mf.
    float2 wrow[8];
    #pragma unroll
    for (int nf = 0; nf < 8; ++nf) {
        int c = nsel * 128 + nf * 16 + (l & 15);
        float b2v = b2[e * MO + c];
        #pragma unroll
        for (int rg = 0; rg < 4; ++rg) {
            acc2[0][nf][rg] += b2v;
            acc2[1][nf][rg] += b2v;
        }
        wrow[nf] = *(const float2*)&woutS[2 * c];
    }
    #pragma unroll
    for (int mf = 0; mf < 2; ++mf)
        #pragma unroll
        for (int rg = 0; rg < 4; ++rg) {
            float m = -1e30f;
            #pragma unroll
            for (int nf = 0; nf < 8; ++nf) m = fmaxf(m, acc2[mf][nf][rg]);
            m = fmaxf(m, __shfl_xor(m, 1, 64));
            m = fmaxf(m, __shfl_xor(m, 2, 64));
            m = fmaxf(m, __shfl_xor(m, 4, 64));
            m = fmaxf(m, __shfl_xor(m, 8, 64));
            int rloc = halfM * 32 + mf * 16 + 4 * (l >> 4) + rg;
            if ((l & 15) == 0) redm[rloc][nsel] = m;
        }
    __syncthreads();
    #pragma unroll
    for (int mf = 0; mf < 2; ++mf)
        #pragma unroll
        for (int rg = 0; rg < 4; ++rg) {
            int rloc = halfM * 32 + mf * 16 + 4 * (l >> 4) + rg;
            float M = fmaxf(redm[rloc][0], redm[rloc][1]);
            float s = 0.f, o0 = 0.f, o1 = 0.f;
            #pragma unroll
            for (int nf = 0; nf < 8; ++nf) {
                float tt = __expf(acc2[mf][nf][rg] - M);
                s += tt;
                o0 = fmaf(tt, wrow[nf].x, o0);
                o1 = fmaf(tt, wrow[nf].y, o1);
            }
            s += __shfl_xor(s, 1, 64); s += __shfl_xor(s, 2, 64);
            s += __shfl_xor(s, 4, 64); s += __shfl_xor(s, 8, 64);
            o0 += __shfl_xor(o0, 1, 64); o0 += __shfl_xor(o0, 2, 64);
            o0 += __shfl_xor(o0, 4, 64); o0 += __shfl_xor(o0, 8, 64);
            o1 += __shfl_xor(o1, 1, 64); o1 += __shfl_xor(o1, 2, 64);
            o1 += __shfl_xor(o1, 4, 64); o1 += __shfl_xor(o1, 8, 64);
            if ((l & 15) == 0) {
                red3[rloc][nsel][0] = s;
                red3[rloc][nsel][1] = o0;
                red3[rloc][nsel][2] = o1;
            }
        }
    __syncthreads();
    if (nsel == 0 && (l & 15) == 0) {
        #pragma unroll
        for (int mf = 0; mf < 2; ++mf)
            #pragma unroll
            for (int rg = 0; rg < 4; ++rg) {
                int rloc = halfM * 32 + mf * 16 + 4 * (l >> 4) + rg;
                float S  = red3[rloc][0][0] + red3[rloc][1][0];
                float O0 = red3[rloc][0][1] + red3[rloc][1][1];
                float O1 = red3[rloc][0][2] + red3[rloc][1][2];
                int gi = row0 + rloc;
                if (gi < cnt) {
                    float g = gate_list[e * BN + gi];
                    int brow = idx_list[e * BN + gi];
                    float inv = 1.f / S;
                    atomicAdd(&out[brow * 2 + 0], g * O0 * inv);
                    atomicAdd(&out[brow * 2 + 1], g * O1 * inv);
                }
            }
    }
}

extern "C" void kernel_launch(void* const* d_in, const int* in_sizes, int n_in,
                              void* d_out, int out_size, void* d_ws, size_t ws_size,
                              hipStream_t stream) {
    const float* x    = (const float*)d_in[0];
    // d_in[1] = cat_prop, unused by the reference
    const float* wg   = (const float*)d_in[2];
    const float* W1   = (const float*)d_in[3];
    const float* b1   = (const float*)d_in[4];
    const float* W2   = (const float*)d_in[5];
    const float* b2   = (const float*)d_in[6];
    const float* Wout = (const float*)d_in[7];
    const float* bout = (const float*)d_in[8];
    float* out = (float*)d_out;

    char* ws = (char*)d_ws;
    int*   gcount    = (int*)(ws + 0);
    int*   gload     = (int*)(ws + 32);
    float* gimp      = (float*)(ws + 64);
    int*   idx_list  = (int*)(ws + 128);
    float* gate_list = (float*)(ws + 128 + sizeof(int) * NE * BN);
    float* W1F       = (float*)(ws + 128 + 8 * NE * BN);                // 2 MB
    float* W2F       = (float*)(ws + 128 + 8 * NE * BN + 64 * 32768);  // 1 MB

    hipMemsetAsync(ws, 0, 128, stream);
    prep_kernel<<<96, 256, 0, stream>>>(W1, W2, W1F, W2F);
    gate_kernel<<<BN / 32, 256, 0, stream>>>(x, wg, gcount, gload, gimp,
                                             idx_list, gate_list, out, bout);
    dim3 eg(BN / 64, NE);
    expert_kernel<<<eg, 256, 0, stream>>>(x, b1, b2, Wout, W1F, W2F,
                                          gcount, gimp, gload,
                                          idx_list, gate_list, out);
}

// Round 5
// 216.566 us; speedup vs baseline: 1.1572x; 1.1572x over previous
//
#include <hip/hip_runtime.h>

#define BN 32768
#define IN 512
#define NE 8
#define NH 128
#define MO 256

typedef const __attribute__((address_space(1))) unsigned int gu32;
typedef __attribute__((address_space(3))) unsigned int lu32;
typedef __attribute__((ext_vector_type(8))) short bf16x8;
typedef __attribute__((ext_vector_type(4))) float f32x4;

// async global->LDS, 16B per lane. LDS dest = wave-uniform base + lane*16.
__device__ __forceinline__ void cp16(const float* g, float* l) {
    __builtin_amdgcn_global_load_lds((gu32*)g, (lu32*)l, 16, 0, 0);
}

// f32 -> bf16 bits, round-to-nearest-even
__device__ __forceinline__ unsigned short f2bf(float f) {
    unsigned int u = __float_as_uint(f);
    u = (u + 0x7fffu + ((u >> 16) & 1u)) >> 16;
    return (unsigned short)u;
}
__device__ __forceinline__ float bf2f(unsigned short h) {
    return __uint_as_float((unsigned int)h << 16);
}

// ---------------- gating via MFMA: logits, top-2, bucketing -----------------
// 64 rows/block, 4 waves; each wave computes a 16-row x 16-col logit tile with
// 16x16x32 bf16-split MFMA (3 terms: hh+hl+lh; error ~5e-6). wg fragment blob
// (hi/lo, 32KB) built in-LDS per block. A-frags read straight from global:
// lane l -> row l&15, k-octet 8*(l>>4) (layout HW-verified by R3's A-path).
// One coalesced pass over x (64MB) -> HBM floor ~10us. f64 fallback only when
// the rank2/rank3 margin < 2e-4 (group-uniform, ~0.02% of rows).
__global__ __launch_bounds__(256) void gate_kernel(
    const float* __restrict__ x, const float* __restrict__ wg,
    int* __restrict__ gcount, int* __restrict__ gload, float* __restrict__ gimp,
    int* __restrict__ idx_list, float* __restrict__ gate_list,
    float* __restrict__ out, const float* __restrict__ bout)
{
    __shared__ __align__(16) char wb[32768];   // [hi 16KB][lo 16KB] B-fragments
    __shared__ int counts_s[NE];
    __shared__ int load_s[NE];
    __shared__ float imp_s[NE];
    __shared__ int base_s[NE];
    __shared__ int rec_e[128];
    __shared__ int rec_p[128];
    __shared__ float rec_g[128];

    int tid = threadIdx.x;
    if (tid < NE) { counts_s[tid] = 0; load_s[tid] = 0; imp_s[tid] = 0.f; }
    if (tid < 128) {  // fused init: out[row, j] = bout[j]
        int row = blockIdx.x * 64 + (tid >> 1);
        out[row * 2 + (tid & 1)] = bout[tid & 1];
    }
    // build wg B-frag blob: 16 k-steps x 64 lane-slots, cols 8..15 zero-padded
    for (int idx = tid; idx < 1024; idx += 256) {
        int ks = idx >> 6, ls = idx & 63;
        int col = ls & 15;
        int kb = 32 * ks + 8 * (ls >> 4);
        unsigned int ph[4], pl[4];
        #pragma unroll
        for (int j = 0; j < 4; ++j) {
            float v0 = (col < 8) ? wg[(kb + 2 * j) * NE + col] : 0.f;
            float v1 = (col < 8) ? wg[(kb + 2 * j + 1) * NE + col] : 0.f;
            unsigned short h0 = f2bf(v0), h1 = f2bf(v1);
            unsigned short l0 = f2bf(v0 - bf2f(h0)), l1 = f2bf(v1 - bf2f(h1));
            ph[j] = (unsigned int)h0 | ((unsigned int)h1 << 16);
            pl[j] = (unsigned int)l0 | ((unsigned int)l1 << 16);
        }
        *(int4*)(wb + ks * 1024 + ls * 16) = make_int4(ph[0], ph[1], ph[2], ph[3]);
        *(int4*)(wb + 16384 + ks * 1024 + ls * 16) = make_int4(pl[0], pl[1], pl[2], pl[3]);
    }
    __syncthreads();

    int w = tid >> 6, l = tid & 63;
    int e = l & 15;
    int rowA = blockIdx.x * 64 + w * 16 + e;   // A-operand row for this lane
    const float* px = x + (size_t)rowA * IN + 8 * (l >> 4);

    f32x4 acc = {};
    #pragma unroll
    for (int ks = 0; ks < 16; ++ks) {
        float4 qa = *(const float4*)(px + 32 * ks);
        float4 qb = *(const float4*)(px + 32 * ks + 4);
        float v[8] = {qa.x, qa.y, qa.z, qa.w, qb.x, qb.y, qb.z, qb.w};
        bf16x8 ah, al;
        #pragma unroll
        for (int i = 0; i < 8; ++i) {
            unsigned short h = f2bf(v[i]);
            ah[i] = (short)h;
            al[i] = (short)f2bf(v[i] - bf2f(h));
        }
        bf16x8 bh = *(const bf16x8*)(wb + ks * 1024 + l * 16);
        bf16x8 bl = *(const bf16x8*)(wb + 16384 + ks * 1024 + l * 16);
        acc = __builtin_amdgcn_mfma_f32_16x16x32_bf16(ah, bh, acc, 0, 0, 0);
        acc = __builtin_amdgcn_mfma_f32_16x16x32_bf16(ah, bl, acc, 0, 0, 0);
        acc = __builtin_amdgcn_mfma_f32_16x16x32_bf16(al, bh, acc, 0, 0, 0);
    }

    // C layout: lane holds expert e = l&15, rows 4*(l>>4)+reg (reg 0..3)
    #pragma unroll
    for (int reg = 0; reg < 4; ++reg) {
        int rloc = w * 16 + 4 * (l >> 4) + reg;
        int row = blockIdx.x * 64 + rloc;
        float lv = (e < 8) ? acc[reg] : -1e30f;

        float v0 = lv; int e0 = e;
        #pragma unroll
        for (int m = 1; m < 8; m <<= 1) {
            float vo = __shfl_xor(v0, m, 64);
            int eo = __shfl_xor(e0, m, 64);
            if (vo > v0 || (vo == v0 && eo < e0)) { v0 = vo; e0 = eo; }
        }
        float v1 = (e == e0 || e >= 8) ? -1e30f : lv; int e1 = e;
        #pragma unroll
        for (int m = 1; m < 8; m <<= 1) {
            float vo = __shfl_xor(v1, m, 64);
            int eo = __shfl_xor(e1, m, 64);
            if (vo > v1 || (vo == v1 && eo < e1)) { v1 = vo; e1 = eo; }
        }
        float v2 = (e == e0 || e == e1 || e >= 8) ? -1e30f : lv;
        #pragma unroll
        for (int m = 1; m < 8; m <<= 1) v2 = fmaxf(v2, __shfl_xor(v2, m, 64));

        double dv0 = v0, dv1 = v1;
        int f0 = e0, f1 = e1;
        if (e < 8 && v1 - v2 < 2e-4f) {   // rare exact recompute (group-uniform)
            const float* xr = x + (size_t)row * IN;
            double d0 = 0, d1 = 0, d2 = 0, d3 = 0;
            for (int k = 0; k < IN; k += 4) {
                float4 xv = *(const float4*)(xr + k);
                d0 = fma((double)xv.x, (double)wg[(k    ) * NE + e], d0);
                d1 = fma((double)xv.y, (double)wg[(k + 1) * NE + e], d1);
                d2 = fma((double)xv.z, (double)wg[(k + 2) * NE + e], d2);
                d3 = fma((double)xv.w, (double)wg[(k + 3) * NE + e], d3);
            }
            double ad = (d0 + d1) + (d2 + d3);
            double w0 = ad; int g0i = e;
            #pragma unroll
            for (int m = 1; m < 8; m <<= 1) {
                double vo = __shfl_xor(w0, m, 64);
                int eo = __shfl_xor(g0i, m, 64);
                if (vo > w0 || (vo == w0 && eo < g0i)) { w0 = vo; g0i = eo; }
            }
            double w1 = (e == g0i) ? -1.0e300 : ad; int g1i = e;
            #pragma unroll
            for (int m = 1; m < 8; m <<= 1) {
                double vo = __shfl_xor(w1, m, 64);
                int eo = __shfl_xor(g1i, m, 64);
                if (vo > w1 || (vo == w1 && eo < g1i)) { w1 = vo; g1i = eo; }
            }
            dv0 = w0; dv1 = w1; f0 = g0i; f1 = g1i;
        }

        if (e == 0) {
            float t1 = expf((float)(dv1 - dv0));
            float s = 1.f + t1;
            float g0 = 1.f / s;
            float g1 = t1 / s;
            atomicAdd(&imp_s[f0], g0);
            atomicAdd(&imp_s[f1], g1);
            if (g0 > 0.f) atomicAdd(&load_s[f0], 1);
            if (g1 > 0.f) atomicAdd(&load_s[f1], 1);
            int p0 = atomicAdd(&counts_s[f0], 1);
            int p1 = atomicAdd(&counts_s[f1], 1);
            int rl = rloc * 2;
            rec_e[rl] = f0; rec_e[rl + 1] = f1;
            rec_g[rl] = g0; rec_g[rl + 1] = g1;
            rec_p[rl] = p0; rec_p[rl + 1] = p1;
        }
    }
    __syncthreads();
    if (tid < NE) {
        base_s[tid] = atomicAdd(&gcount[tid], counts_s[tid]);
        atomicAdd(&gimp[tid], imp_s[tid]);
        atomicAdd(&gload[tid], load_s[tid]);
    }
    __syncthreads();
    if (tid < 128) {
        int ee = rec_e[tid];
        int pos = base_s[ee] + rec_p[tid];
        int rw = blockIdx.x * 64 + (tid >> 1);
        idx_list[ee * BN + pos] = rw;
        gate_list[ee * BN + pos] = rec_g[tid];
    }
}

// ---------------- weight prep: split bf16 + MFMA-fragment-order blobs -------
__global__ __launch_bounds__(256) void prep_kernel(
    const float* __restrict__ W1, const float* __restrict__ W2,
    float* __restrict__ W1F, float* __restrict__ W2F)
{
    __shared__ __align__(16) char pb[32768];
    int t = threadIdx.x, b = blockIdx.x;
    if (b < 64) {                       // W1: e = b>>3, ktile(64 k) = b&7
        int e = b >> 3, kt = b & 7;
        const float* src = W1 + ((size_t)e * IN + kt * 64) * NH;
        #pragma unroll
        for (int p = 0; p < 8; ++p) {
            int li = p * 256 + t;
            float4 q = *(const float4*)(src + li * 4);
            int kl = li >> 5, n0 = (li & 31) * 4;
            int ks = kl >> 5, g = (kl >> 3) & 3, kb = (kl & 7) * 2;
            float vv[4] = {q.x, q.y, q.z, q.w};
            #pragma unroll
            for (int j = 0; j < 4; ++j) {
                int n = n0 + j;
                int off = (((ks * 8 + (n >> 4)) * 64) + (n & 15) + 16 * g) * 16 + kb;
                unsigned short hh = f2bf(vv[j]);
                unsigned short hl = f2bf(vv[j] - bf2f(hh));
                *(unsigned short*)(pb + off) = hh;
                *(unsigned short*)(pb + 16384 + off) = hl;
            }
        }
        __syncthreads();
        float* dst = W1F + (size_t)b * 8192;
        #pragma unroll
        for (int p = 0; p < 8; ++p) {
            int li = p * 256 + t;
            *(int4*)(dst + li * 4) = *(const int4*)(pb + li * 16);
        }
    } else if (b < 96) {                // W2: e = bi>>2, ktile(32 k) = bi&3
        int bi = b - 64;
        int e = bi >> 2, kt = bi & 3;
        const float* src = W2 + ((size_t)e * NH + kt * 32) * MO;
        #pragma unroll
        for (int p = 0; p < 8; ++p) {
            int li = p * 256 + t;
            float4 q = *(const float4*)(src + li * 4);
            int kl = li >> 6, n0 = (li & 63) * 4;
            int g = kl >> 3, kb = (kl & 7) * 2;
            float vv[4] = {q.x, q.y, q.z, q.w};
            #pragma unroll
            for (int j = 0; j < 4; ++j) {
                int n = n0 + j;
                int off = ((n >> 4) * 64 + (n & 15) + 16 * g) * 16 + kb;
                unsigned short hh = f2bf(vv[j]);
                unsigned short hl = f2bf(vv[j] - bf2f(hh));
                *(unsigned short*)(pb + off) = hh;
                *(unsigned short*)(pb + 16384 + off) = hl;
            }
        }
        __syncthreads();
        float* dst = W2F + (size_t)bi * 8192;
        #pragma unroll
        for (int p = 0; p < 8; ++p) {
            int li = p * 256 + t;
            *(int4*)(dst + li * 4) = *(const int4*)(pb + li * 16);
        }
    }
}

// ---------------- expert compute: split-bf16 MFMA, 64-row tiles -------------
// R2 structure (measured 86.5us): cooperative A-staging + blob DMA, 2 barriers
// per K-tile, LDS = 66.5KB -> 2 blocks/CU. Loss fused into block (0,0).
#define OFF_AH 0
#define OFF_AL 8192
#define OFF_B1 16384
#define OFF_HH 0
#define OFF_HL 16384
#define OFF_B2 32768

__global__ __launch_bounds__(256, 2) void expert_kernel(
    const float* __restrict__ x,
    const float* __restrict__ b1, const float* __restrict__ b2,
    const float* __restrict__ Wout,
    const float* __restrict__ W1F, const float* __restrict__ W2F,
    const int* __restrict__ gcount,
    const float* __restrict__ gimp, const int* __restrict__ gload,
    const int* __restrict__ idx_list, const float* __restrict__ gate_list,
    float* __restrict__ out)
{
    __shared__ __align__(16) char smx[66560];   // stage1 48K | stage2 64K | z 65K
    __shared__ float woutS[512];

    int e = blockIdx.y;
    int cnt = gcount[e];
    int row0 = blockIdx.x * 64;
    // fused load-balancing loss (one thread device-wide)
    if (e == 0 && blockIdx.x == 0 && threadIdx.x == 0) {
        float mi = 0.f, ml = 0.f;
        for (int k = 0; k < NE; ++k) { mi += gimp[k]; ml += (float)gload[k]; }
        mi *= 0.125f; ml *= 0.125f;
        float vi = 0.f, vl = 0.f;
        for (int k = 0; k < NE; ++k) {
            float d = gimp[k] - mi;  vi += d * d;
            float d2 = (float)gload[k] - ml; vl += d2 * d2;
        }
        vi *= (1.f / 7.f); vl *= (1.f / 7.f);
        out[BN * 2] = (vi / (mi * mi + 1e-10f) + vl / (ml * ml + 1e-10f)) * 0.01f;
    }
    if (row0 >= cnt) return;
    int t = threadIdx.x;
    int l = t & 63, w = t >> 6;

    woutS[t] = Wout[t];
    woutS[256 + t] = Wout[256 + t];

    // staging decomposition: thread -> (mfrag, row-low, k-group)
    int s_mf = t >> 6;
    int s_r  = t & 15;
    int s_g  = (t >> 4) & 3;
    int rloc = s_mf * 16 + s_r;
    int sgi = row0 + rloc; if (sgi >= cnt) sgi = cnt - 1;
    const float* xrow = x + (size_t)idx_list[e * BN + sgi] * IN;

    int mbase = (w & 1) * 2;   // wave's M-frags: rows (w&1)*32..+31
    int nsel  = w >> 1;        // wave's col half

    // ---- stage 1: H[64x128] = relu(X @ W1 + b1), K=512 in 8 tiles of 64 ----
    f32x4 acc1[2][4] = {};
    for (int kt = 0; kt < 8; ++kt) {
        {   // W1 fragment blob (32KB) via async DMA
            const float* gb = W1F + (size_t)(e * 8 + kt) * 8192;
            float* lb = (float*)(smx + OFF_B1);
            #pragma unroll
            for (int p = 0; p < 8; ++p)
                cp16(gb + (p * 256 + t) * 4, lb + (p * 256 + t) * 4);
        }
        // x -> split-bf16 A-fragments (lane-linear b128 writes)
        #pragma unroll
        for (int ks = 0; ks < 2; ++ks) {
            int k = kt * 64 + ks * 32 + s_g * 8;
            float4 qa = *(const float4*)(xrow + k);
            float4 qb = *(const float4*)(xrow + k + 4);
            float vv[8] = {qa.x, qa.y, qa.z, qa.w, qb.x, qb.y, qb.z, qb.w};
            unsigned int dh[4], dl[4];
            #pragma unroll
            for (int j = 0; j < 4; ++j) {
                unsigned short h0 = f2bf(vv[2 * j]);
                unsigned short h1 = f2bf(vv[2 * j + 1]);
                unsigned short l0 = f2bf(vv[2 * j] - bf2f(h0));
                unsigned short l1 = f2bf(vv[2 * j + 1] - bf2f(h1));
                dh[j] = (unsigned int)h0 | ((unsigned int)h1 << 16);
                dl[j] = (unsigned int)l0 | ((unsigned int)l1 << 16);
            }
            int slot = ((ks * 4 + s_mf) * 64 + (s_r + 16 * s_g)) * 16;
            *(int4*)(smx + OFF_AH + slot) = make_int4(dh[0], dh[1], dh[2], dh[3]);
            *(int4*)(smx + OFF_AL + slot) = make_int4(dl[0], dl[1], dl[2], dl[3]);
        }
        __syncthreads();
        #pragma unroll
        for (int ks = 0; ks < 2; ++ks) {
            bf16x8 ah[2], al[2];
            #pragma unroll
            for (int mf = 0; mf < 2; ++mf) {
                int ao = ((ks * 4 + mbase + mf) * 64 + l) * 16;
                ah[mf] = *(const bf16x8*)(smx + OFF_AH + ao);
                al[mf] = *(const bf16x8*)(smx + OFF_AL + ao);
            }
            #pragma unroll
            for (int nf = 0; nf < 4; ++nf) {
                int bo = ((ks * 8 + nsel * 4 + nf) * 64 + l) * 16;
                bf16x8 bh = *(const bf16x8*)(smx + OFF_B1 + bo);
                bf16x8 bl = *(const bf16x8*)(smx + OFF_B1 + 16384 + bo);
                #pragma unroll
                for (int mf = 0; mf < 2; ++mf) {
                    acc1[mf][nf] = __builtin_amdgcn_mfma_f32_16x16x32_bf16(ah[mf], bh, acc1[mf][nf], 0, 0, 0);
                    acc1[mf][nf] = __builtin_amdgcn_mfma_f32_16x16x32_bf16(ah[mf], bl, acc1[mf][nf], 0, 0, 0);
                    acc1[mf][nf] = __builtin_amdgcn_mfma_f32_16x16x32_bf16(al[mf], bh, acc1[mf][nf], 0, 0, 0);
                    acc1[mf][nf] = __builtin_amdgcn_mfma_f32_16x16x32_bf16(al[mf], bl, acc1[mf][nf], 0, 0, 0);
                }
            }
        }
        __syncthreads();
    }

    // ---- relu(+b1), split, write H as stage-2 A-fragments ----
    #pragma unroll
    for (int mf = 0; mf < 2; ++mf) {
        int mf2 = (w & 1) * 2 + mf;
        int rlow = 4 * (l >> 4);
        #pragma unroll
        for (int nf = 0; nf < 4; ++nf) {
            int c = nsel * 64 + nf * 16 + (l & 15);
            float b1v = b1[e * NH + c];
            int ks2 = c >> 5;
            int g2 = (c >> 3) & 3;
            int boff = ((ks2 * 4 + mf2) * 64) * 16 + (c & 7) * 2;
            #pragma unroll
            for (int rg = 0; rg < 4; ++rg) {
                float v = fmaxf(acc1[mf][nf][rg] + b1v, 0.f);
                unsigned short hh = f2bf(v);
                unsigned short hl = f2bf(v - bf2f(hh));
                int off = boff + ((rlow + rg) + 16 * g2) * 16;
                *(unsigned short*)(smx + OFF_HH + off) = hh;
                *(unsigned short*)(smx + OFF_HL + off) = hl;
            }
        }
    }
    __syncthreads();

    // ---- stage 2: Z[64x256] = H @ W2, K=128 in 4 tiles of 32 ----
    f32x4 acc2[2][8] = {};
    for (int kt2 = 0; kt2 < 4; ++kt2) {
        {
            const float* gb = W2F + (size_t)(e * 4 + kt2) * 8192;
            float* lb = (float*)(smx + OFF_B2);
            #pragma unroll
            for (int p = 0; p < 8; ++p)
                cp16(gb + (p * 256 + t) * 4, lb + (p * 256 + t) * 4);
        }
        __syncthreads();
        bf16x8 ah[2], al[2];
        #pragma unroll
        for (int mf = 0; mf < 2; ++mf) {
            int ao = ((kt2 * 4 + (w & 1) * 2 + mf) * 64 + l) * 16;
            ah[mf] = *(const bf16x8*)(smx + OFF_HH + ao);
            al[mf] = *(const bf16x8*)(smx + OFF_HL + ao);
        }
        #pragma unroll
        for (int nf = 0; nf < 8; ++nf) {
            int bo = ((nsel * 8 + nf) * 64 + l) * 16;
            bf16x8 bh = *(const bf16x8*)(smx + OFF_B2 + bo);
            bf16x8 bl = *(const bf16x8*)(smx + OFF_B2 + 16384 + bo);
            #pragma unroll
            for (int mf = 0; mf < 2; ++mf) {
                acc2[mf][nf] = __builtin_amdgcn_mfma_f32_16x16x32_bf16(ah[mf], bh, acc2[mf][nf], 0, 0, 0);
                acc2[mf][nf] = __builtin_amdgcn_mfma_f32_16x16x32_bf16(ah[mf], bl, acc2[mf][nf], 0, 0, 0);
                acc2[mf][nf] = __builtin_amdgcn_mfma_f32_16x16x32_bf16(al[mf], bh, acc2[mf][nf], 0, 0, 0);
                acc2[mf][nf] = __builtin_amdgcn_mfma_f32_16x16x32_bf16(al[mf], bl, acc2[mf][nf], 0, 0, 0);
            }
        }
        __syncthreads();
    }

    // ---- epilogue: z(+b2) -> LDS, row softmax fused with @Wout ----
    float* zl = (float*)smx;
    #pragma unroll
    for (int mf = 0; mf < 2; ++mf) {
        int rbase = (w & 1) * 32 + mf * 16 + 4 * (l >> 4);
        #pragma unroll
        for (int nf = 0; nf < 8; ++nf) {
            int c = nsel * 128 + nf * 16 + (l & 15);
            float b2v = b2[e * MO + c];
            #pragma unroll
            for (int rg = 0; rg < 4; ++rg)
                zl[(rbase + rg) * 260 + c] = acc2[mf][nf][rg] + b2v;
        }
    }
    __syncthreads();

    // 4 lanes per row, interleaved cols (c0 + 4j) -> distinct banks
    int rr = w * 16 + (l >> 2);
    int c0 = l & 3;
    float vreg[64];
    float m = -1e30f;
    #pragma unroll
    for (int j = 0; j < 64; ++j) {
        vreg[j] = zl[rr * 260 + c0 + 4 * j];
        m = fmaxf(m, vreg[j]);
    }
    m = fmaxf(m, __shfl_xor(m, 1, 64));
    m = fmaxf(m, __shfl_xor(m, 2, 64));
    float s = 0.f, o0 = 0.f, o1 = 0.f;
    #pragma unroll
    for (int j = 0; j < 64; ++j) {
        float tt = __expf(vreg[j] - m);
        s += tt;
        float2 wv = *(const float2*)&woutS[(c0 + 4 * j) * 2];
        o0 = fmaf(tt, wv.x, o0);
        o1 = fmaf(tt, wv.y, o1);
    }
    s  += __shfl_xor(s, 1, 64);  s  += __shfl_xor(s, 2, 64);
    o0 += __shfl_xor(o0, 1, 64); o0 += __shfl_xor(o0, 2, 64);
    o1 += __shfl_xor(o1, 1, 64); o1 += __shfl_xor(o1, 2, 64);
    if (c0 == 0) {
        int gi = row0 + rr;
        if (gi < cnt) {
            float g = gate_list[e * BN + gi];
            int brow = idx_list[e * BN + gi];
            float inv = 1.f / s;
            atomicAdd(&out[brow * 2 + 0], g * o0 * inv);
            atomicAdd(&out[brow * 2 + 1], g * o1 * inv);
        }
    }
}

extern "C" void kernel_launch(void* const* d_in, const int* in_sizes, int n_in,
                              void* d_out, int out_size, void* d_ws, size_t ws_size,
                              hipStream_t stream) {
    const float* x    = (const float*)d_in[0];
    // d_in[1] = cat_prop, unused by the reference
    const float* wg   = (const float*)d_in[2];
    const float* W1   = (const float*)d_in[3];
    const float* b1   = (const float*)d_in[4];
    const float* W2   = (const float*)d_in[5];
    const float* b2   = (const float*)d_in[6];
    const float* Wout = (const float*)d_in[7];
    const float* bout = (const float*)d_in[8];
    float* out = (float*)d_out;

    char* ws = (char*)d_ws;
    int*   gcount    = (int*)(ws + 0);
    int*   gload     = (int*)(ws + 32);
    float* gimp      = (float*)(ws + 64);
    int*   idx_list  = (int*)(ws + 128);
    float* gate_list = (float*)(ws + 128 + sizeof(int) * NE * BN);
    float* W1F       = (float*)(ws + 128 + 8 * NE * BN);                // 2 MB
    float* W2F       = (float*)(ws + 128 + 8 * NE * BN + 64 * 32768);  // 1 MB

    hipMemsetAsync(ws, 0, 128, stream);
    prep_kernel<<<96, 256, 0, stream>>>(W1, W2, W1F, W2F);
    gate_kernel<<<BN / 64, 256, 0, stream>>>(x, wg, gcount, gload, gimp,
                                             idx_list, gate_list, out, bout);
    dim3 eg(BN / 64, NE);
    expert_kernel<<<eg, 256, 0, stream>>>(x, b1, b2, Wout, W1F, W2F,
                                          gcount, gimp, gload,
                                          idx_list, gate_list, out);
}